// Round 8
// baseline (245.631 us; speedup 1.0000x reference)
//
#include <hip/hip_runtime.h>
#include <hip/hip_cooperative_groups.h>
#include <hip/hip_bf16.h>

namespace cg = cooperative_groups;

// Problem constants: B=2, C=64, H=64, W=64 -> N=8192 tokens, DH=32.
#define N_TOK   8192
#define DH      32
#define CCH     64
#define HWSZ    4096
#define LOG2E   1.4426950408889634f
#define NCH_Z   32     // i-chunks in pass A (ilen = 256)
#define NCH_O   32     // j-chunks in pass B (jlen = 256)
#define ITILE   64     // i-rows per wave in pass B (4 Q fragments)
#define GRID_CP 512    // cooperative grid: 2 blocks/CU — legal for any VGPR<=256

typedef __attribute__((ext_vector_type(8))) short  bf16x8;
typedef __attribute__((ext_vector_type(4))) short  bf16x4;
typedef __attribute__((ext_vector_type(4))) float  f32x4;

static __device__ __forceinline__ short f2bf(float f) {
    __hip_bfloat16 h = __float2bfloat16(f);
    return __builtin_bit_cast(short, h);
}
static __device__ __forceinline__ float bf2f(short s) {
    unsigned u = ((unsigned)(unsigned short)s) << 16;
    return __builtin_bit_cast(float, u);
}

// A/B fragment for mfma_f32_16x16x32_bf16 from row-major [rows][32] bf16:
// lane l supplies row row0+(l&15), k = 8*(l>>4)..+8 (16B load).
static __device__ __forceinline__ bf16x8 load_frag8(const __hip_bfloat16* __restrict__ base,
                                                    int row0, int l) {
    const __hip_bfloat16* p = base + (size_t)(row0 + (l & 15)) * DH + ((l >> 4) << 3);
    return *reinterpret_cast<const bf16x8*>(p);
}

// ===========================================================================
// Cooperative single-kernel pipeline. 512 blocks x 256 threads, grid-stride
// phases, LDS overlaid (25 KB). grid.sync() between phases.
// ===========================================================================
__global__ __launch_bounds__(256, 2) void k_fused(
        const float* __restrict__ x,
        const float* __restrict__ w1, const float* __restrict__ b1,
        const float* __restrict__ w2, const float* __restrict__ b2,
        const float* __restrict__ w3, const float* __restrict__ b3,
        const float* __restrict__ w4, const float* __restrict__ b4,
        __hip_bfloat16* __restrict__ Qb, __hip_bfloat16* __restrict__ Kb,
        __hip_bfloat16* __restrict__ VTb, float* __restrict__ Zp,
        __hip_bfloat16* __restrict__ oTp, float* __restrict__ y) {
    __shared__ __align__(16) char smem[25088];
    cg::grid_group grid = cg::this_grid();
    const int t   = threadIdx.x;
    const int blk = blockIdx.x;
    const int ng  = gridDim.x;

    // ================= Phase 1: qkv =================
    {
        float4 (*w1s)[32] = (float4(*)[32])(smem);
        float4 (*w2s)[32] = (float4(*)[32])(smem + 8192);
        float4 (*w3s)[32] = (float4(*)[32])(smem + 16384);
        short  (*vt)[8]   = (short (*)[8])(smem + 24576);
        for (int i = t; i < 512; i += 256) {
            int cg_ = i >> 5, d = i & 31;
            w1s[cg_][d] = *reinterpret_cast<const float4*>(w1 + d * CCH + cg_ * 4);
            w2s[cg_][d] = *reinterpret_cast<const float4*>(w2 + d * CCH + cg_ * 4);
            w3s[cg_][d] = *reinterpret_cast<const float4*>(w3 + d * CCH + cg_ * 4);
        }
        __syncthreads();
        int d = t & 31, nr = t >> 5;
        for (int u = blk; u < N_TOK / 8; u += ng) {
            int n0 = u * 8;
            int n = n0 + nr;
            int b = n >> 12, hw = n & 4095;
            const float* xp = x + (size_t)b * (CCH * HWSZ) + hw;
            float aq = b1[d], ak = b2[d], av = b3[d];
            #pragma unroll
            for (int cg_ = 0; cg_ < 16; ++cg_) {
                float x0 = xp[(cg_ * 4 + 0) * HWSZ];
                float x1 = xp[(cg_ * 4 + 1) * HWSZ];
                float x2 = xp[(cg_ * 4 + 2) * HWSZ];
                float x3 = xp[(cg_ * 4 + 3) * HWSZ];
                float4 a = w1s[cg_][d];
                aq = fmaf(a.x, x0, aq); aq = fmaf(a.y, x1, aq);
                aq = fmaf(a.z, x2, aq); aq = fmaf(a.w, x3, aq);
                float4 bb = w2s[cg_][d];
                ak = fmaf(bb.x, x0, ak); ak = fmaf(bb.y, x1, ak);
                ak = fmaf(bb.z, x2, ak); ak = fmaf(bb.w, x3, ak);
                float4 cc = w3s[cg_][d];
                av = fmaf(cc.x, x0, av); av = fmaf(cc.y, x1, av);
                av = fmaf(cc.z, x2, av); av = fmaf(cc.w, x3, av);
            }
            Qb[(size_t)n * DH + d] = __float2bfloat16(aq * LOG2E);
            Kb[(size_t)n * DH + d] = __float2bfloat16(ak);
            vt[d][nr] = f2bf(av);
            __syncthreads();
            if (t < 32) {
                bf16x8 row = *reinterpret_cast<const bf16x8*>(&vt[t][0]);
                *reinterpret_cast<bf16x8*>(VTb + (size_t)t * N_TOK + n0) = row;
            }
            __syncthreads();
        }
    }
    grid.sync();

    // ================= Phase 2: Zpart =================
    {
        int l = t & 63, w = t >> 6;
        const int ilen = N_TOK / NCH_Z;      // 256
        const f32x4 z4 = {0.f, 0.f, 0.f, 0.f};
        for (int u = blk * 4 + w; u < 128 * NCH_Z; u += ng * 4) {
            int jt = u >> 5;                 // 0..127
            int ic = u & 31;                 // 0..31
            int j0 = jt * 64;
            int i0 = ic * ilen;
            bf16x8 ka[4];
            #pragma unroll
            for (int f = 0; f < 4; ++f) ka[f] = load_frag8(Kb, j0 + f * 16, l);
            float zac[16];
            #pragma unroll
            for (int k = 0; k < 16; ++k) zac[k] = 0.f;
            #pragma unroll 2
            for (int i = i0; i < i0 + ilen; i += 16) {
                bf16x8 qf = load_frag8(Qb, i, l);
                #pragma unroll
                for (int f = 0; f < 4; ++f) {
                    f32x4 s = __builtin_amdgcn_mfma_f32_16x16x32_bf16(ka[f], qf, z4, 0, 0, 0);
                    #pragma unroll
                    for (int r = 0; r < 4; ++r)
                        zac[f * 4 + r] += __builtin_amdgcn_exp2f(s[r]);
                }
            }
            #pragma unroll
            for (int k = 0; k < 16; ++k) {
                float z = zac[k];
                z += __shfl_xor(z, 1); z += __shfl_xor(z, 2);
                z += __shfl_xor(z, 4); z += __shfl_xor(z, 8);
                zac[k] = z;
            }
            if ((l & 15) == 0) {
                int jr = (l >> 4) * 4;
                #pragma unroll
                for (int f = 0; f < 4; ++f)
                    #pragma unroll
                    for (int r = 0; r < 4; ++r)
                        Zp[(size_t)ic * N_TOK + j0 + f * 16 + jr + r] = zac[f * 4 + r];
            }
        }
    }
    grid.sync();

    // ================= Phase 3: attn (PV) =================
    {
        float* rzs = (float*)smem;           // 1 KB
        const int jlen = N_TOK / NCH_O;      // 256
        const f32x4 z4 = {0.f, 0.f, 0.f, 0.f};
        int l = t & 63;
        int lo16 = l & 15, hi4 = (l >> 4) << 2;
        const __hip_bfloat16* v0p = VTb + (size_t)lo16 * N_TOK;
        const __hip_bfloat16* v1p = VTb + (size_t)(lo16 + 16) * N_TOK;
        for (int u = blk; u < 1024; u += ng) {
            int jc  = u & 31;
            int itg = u >> 5;
            int j0c = jc * jlen;
            {   // Z reduction for this j-chunk (fixed order -> deterministic)
                float z = 0.f;
                #pragma unroll 8
                for (int c = 0; c < NCH_Z; ++c) z += Zp[(size_t)c * N_TOK + j0c + t];
                rzs[t] = __builtin_amdgcn_rcpf(z);
            }
            __syncthreads();
            int it = itg * 4 + (t >> 6);
            int i0 = it * ITILE;
            bf16x8 qb[4];
            #pragma unroll
            for (int f = 0; f < 4; ++f) qb[f] = load_frag8(Qb, i0 + f * 16, l);
            f32x4 acc0[4], acc1[4];
            #pragma unroll
            for (int f = 0; f < 4; ++f) { acc0[f] = {0.f,0.f,0.f,0.f}; acc1[f] = {0.f,0.f,0.f,0.f}; }
            #pragma unroll 2
            for (int jl = 0; jl < jlen; jl += 16) {
                int j = j0c + jl;
                f32x4 rz = *reinterpret_cast<const f32x4*>(&rzs[jl + hi4]);
                bf16x8 kaf = load_frag8(Kb, j, l);
                bf16x4 va0 = *reinterpret_cast<const bf16x4*>(v0p + j + hi4);
                bf16x4 va1 = *reinterpret_cast<const bf16x4*>(v1p + j + hi4);
                #pragma unroll
                for (int f = 0; f < 4; ++f) {
                    f32x4 s = __builtin_amdgcn_mfma_f32_16x16x32_bf16(kaf, qb[f], z4, 0, 0, 0);
                    bf16x4 e;
                    #pragma unroll
                    for (int r = 0; r < 4; ++r)
                        e[r] = f2bf(__builtin_amdgcn_exp2f(s[r]) * rz[r]);
                    acc0[f] = __builtin_amdgcn_mfma_f32_16x16x16bf16_1k(va0, e, acc0[f], 0, 0, 0);
                    acc1[f] = __builtin_amdgcn_mfma_f32_16x16x16bf16_1k(va1, e, acc1[f], 0, 0, 0);
                }
            }
            int icol = i0 + lo16;
            #pragma unroll
            for (int f = 0; f < 4; ++f) {
                #pragma unroll
                for (int r = 0; r < 4; ++r) {
                    oTp[(size_t)(jc * DH + hi4 + r)      * N_TOK + icol + f * 16] =
                        __float2bfloat16(acc0[f][r]);
                    oTp[(size_t)(jc * DH + 16 + hi4 + r) * N_TOK + icol + f * 16] =
                        __float2bfloat16(acc1[f][r]);
                }
            }
            __syncthreads();   // rzs reused next unit
        }
    }
    grid.sync();

    // ================= Phase 4: reduce + conv4 + residual =================
    {
        float (*w4s)[32]  = (float(*)[32])(smem);          // 8 KB
        float (*tile)[36] = (float(*)[36])(smem + 8192);   // 4.6 KB
        {   // stage w4 (2048 f32)
            const float4* w4v = reinterpret_cast<const float4*>(w4);
            float4* dst = reinterpret_cast<float4*>(&w4s[0][0]);
            dst[t * 2]     = w4v[t * 2];
            dst[t * 2 + 1] = w4v[t * 2 + 1];
        }
        __syncthreads();
        for (int u = blk; u < 256; u += ng) {
            int n0 = u * 32;
            int d = t >> 3, seg = t & 7;      // 4 tokens per seg
            float s[4];
            #pragma unroll
            for (int k = 0; k < 4; ++k) s[k] = 0.f;
            #pragma unroll 4
            for (int c = 0; c < NCH_O; ++c) {
                bf16x4 v = *reinterpret_cast<const bf16x4*>(
                    oTp + ((size_t)c * DH + d) * N_TOK + n0 + seg * 4);
                #pragma unroll
                for (int k = 0; k < 4; ++k) s[k] += bf2f(v[k]);
            }
            #pragma unroll
            for (int k = 0; k < 4; ++k) tile[d][seg * 4 + k] = s[k];
            __syncthreads();
            int n_l = t & 31, cgr = t >> 5;
            int n = n0 + n_l, b = n >> 12, hw = n & 4095;
            #pragma unroll
            for (int ci = 0; ci < 8; ++ci) {
                int c = cgr * 8 + ci;
                float acc = b4[c];
                #pragma unroll
                for (int dd = 0; dd < 32; ++dd)
                    acc = fmaf(w4s[c][dd], tile[dd][n_l], acc);
                int idx = b * (CCH * HWSZ) + c * HWSZ + hw;
                y[idx] = acc + x[idx];
            }
            __syncthreads();
        }
    }
}

// ===========================================================================
// Fallback pipeline (R6, verified 67.4us) — used if cooperative launch fails.
// ===========================================================================
__global__ __launch_bounds__(256) void k_qkv(
        const float* __restrict__ x,
        const float* __restrict__ w1, const float* __restrict__ b1,
        const float* __restrict__ w2, const float* __restrict__ b2,
        const float* __restrict__ w3, const float* __restrict__ b3,
        __hip_bfloat16* __restrict__ Qb, __hip_bfloat16* __restrict__ Kb,
        __hip_bfloat16* __restrict__ VTb) {
    __shared__ float4 w1s[16][32];
    __shared__ float4 w2s[16][32];
    __shared__ float4 w3s[16][32];
    __shared__ short  vt[32][8];
    int t = threadIdx.x;
    for (int i = t; i < 512; i += 256) {
        int cg_ = i >> 5, d = i & 31;
        w1s[cg_][d] = *reinterpret_cast<const float4*>(w1 + d * CCH + cg_ * 4);
        w2s[cg_][d] = *reinterpret_cast<const float4*>(w2 + d * CCH + cg_ * 4);
        w3s[cg_][d] = *reinterpret_cast<const float4*>(w3 + d * CCH + cg_ * 4);
    }
    __syncthreads();
    int d = t & 31, nr = t >> 5;
    int n0 = blockIdx.x * 8;
    int n = n0 + nr;
    int b = n >> 12, hw = n & 4095;
    const float* xp = x + (size_t)b * (CCH * HWSZ) + hw;
    float aq = b1[d], ak = b2[d], av = b3[d];
    #pragma unroll
    for (int cg_ = 0; cg_ < 16; ++cg_) {
        float x0 = xp[(cg_ * 4 + 0) * HWSZ];
        float x1 = xp[(cg_ * 4 + 1) * HWSZ];
        float x2 = xp[(cg_ * 4 + 2) * HWSZ];
        float x3 = xp[(cg_ * 4 + 3) * HWSZ];
        float4 a = w1s[cg_][d];
        aq = fmaf(a.x, x0, aq); aq = fmaf(a.y, x1, aq);
        aq = fmaf(a.z, x2, aq); aq = fmaf(a.w, x3, aq);
        float4 bb = w2s[cg_][d];
        ak = fmaf(bb.x, x0, ak); ak = fmaf(bb.y, x1, ak);
        ak = fmaf(bb.z, x2, ak); ak = fmaf(bb.w, x3, ak);
        float4 cc = w3s[cg_][d];
        av = fmaf(cc.x, x0, av); av = fmaf(cc.y, x1, av);
        av = fmaf(cc.z, x2, av); av = fmaf(cc.w, x3, av);
    }
    Qb[(size_t)n * DH + d] = __float2bfloat16(aq * LOG2E);
    Kb[(size_t)n * DH + d] = __float2bfloat16(ak);
    vt[d][nr] = f2bf(av);
    __syncthreads();
    if (t < 32) {
        bf16x8 row = *reinterpret_cast<const bf16x8*>(&vt[t][0]);
        *reinterpret_cast<bf16x8*>(VTb + (size_t)t * N_TOK + n0) = row;
    }
}

__global__ __launch_bounds__(256) void k_zpart(
        const __hip_bfloat16* __restrict__ Qb, const __hip_bfloat16* __restrict__ Kb,
        float* __restrict__ Zpart) {
    int l  = threadIdx.x & 63;
    int gw = blockIdx.x * 4 + (threadIdx.x >> 6);
    int jt = gw >> 5;
    int ic = gw & 31;
    int j0 = jt * 64;
    const int ilen = N_TOK / NCH_Z;
    int i0 = ic * ilen;
    bf16x8 ka[4];
    #pragma unroll
    for (int f = 0; f < 4; ++f) ka[f] = load_frag8(Kb, j0 + f * 16, l);
    float zac[16];
    #pragma unroll
    for (int k = 0; k < 16; ++k) zac[k] = 0.f;
    const f32x4 z4 = {0.f, 0.f, 0.f, 0.f};
    #pragma unroll 2
    for (int i = i0; i < i0 + ilen; i += 16) {
        bf16x8 qf = load_frag8(Qb, i, l);
        #pragma unroll
        for (int f = 0; f < 4; ++f) {
            f32x4 s = __builtin_amdgcn_mfma_f32_16x16x32_bf16(ka[f], qf, z4, 0, 0, 0);
            #pragma unroll
            for (int r = 0; r < 4; ++r)
                zac[f * 4 + r] += __builtin_amdgcn_exp2f(s[r]);
        }
    }
    #pragma unroll
    for (int k = 0; k < 16; ++k) {
        float z = zac[k];
        z += __shfl_xor(z, 1); z += __shfl_xor(z, 2);
        z += __shfl_xor(z, 4); z += __shfl_xor(z, 8);
        zac[k] = z;
    }
    if ((l & 15) == 0) {
        int jr = (l >> 4) * 4;
        #pragma unroll
        for (int f = 0; f < 4; ++f)
            #pragma unroll
            for (int r = 0; r < 4; ++r)
                Zpart[(size_t)ic * N_TOK + j0 + f * 16 + jr + r] = zac[f * 4 + r];
    }
}

__global__ __launch_bounds__(256) void k_attn(
        const __hip_bfloat16* __restrict__ Qb, const __hip_bfloat16* __restrict__ Kb,
        const __hip_bfloat16* __restrict__ VTb, const float* __restrict__ Zpart,
        __hip_bfloat16* __restrict__ oTp) {
    __shared__ float rzs[256];
    int t = threadIdx.x;
    int jc  = blockIdx.x & 31;
    int itg = blockIdx.x >> 5;
    const int jlen = N_TOK / NCH_O;
    int j0c = jc * jlen;
    {
        float z = 0.f;
        #pragma unroll 8
        for (int c = 0; c < NCH_Z; ++c) z += Zpart[(size_t)c * N_TOK + j0c + t];
        rzs[t] = __builtin_amdgcn_rcpf(z);
    }
    __syncthreads();
    int l = t & 63;
    int it = itg * 4 + (t >> 6);
    int i0 = it * ITILE;
    bf16x8 qb[4];
    #pragma unroll
    for (int f = 0; f < 4; ++f) qb[f] = load_frag8(Qb, i0 + f * 16, l);
    f32x4 acc0[4], acc1[4];
    #pragma unroll
    for (int f = 0; f < 4; ++f) { acc0[f] = {0.f,0.f,0.f,0.f}; acc1[f] = {0.f,0.f,0.f,0.f}; }
    const f32x4 z4 = {0.f, 0.f, 0.f, 0.f};
    int lo16 = l & 15, hi4 = (l >> 4) << 2;
    const __hip_bfloat16* v0p = VTb + (size_t)lo16 * N_TOK;
    const __hip_bfloat16* v1p = VTb + (size_t)(lo16 + 16) * N_TOK;
    #pragma unroll 2
    for (int jl = 0; jl < jlen; jl += 16) {
        int j = j0c + jl;
        f32x4 rz = *reinterpret_cast<const f32x4*>(&rzs[jl + hi4]);
        bf16x8 kaf = load_frag8(Kb, j, l);
        bf16x4 va0 = *reinterpret_cast<const bf16x4*>(v0p + j + hi4);
        bf16x4 va1 = *reinterpret_cast<const bf16x4*>(v1p + j + hi4);
        #pragma unroll
        for (int f = 0; f < 4; ++f) {
            f32x4 s = __builtin_amdgcn_mfma_f32_16x16x32_bf16(kaf, qb[f], z4, 0, 0, 0);
            bf16x4 e;
            #pragma unroll
            for (int r = 0; r < 4; ++r)
                e[r] = f2bf(__builtin_amdgcn_exp2f(s[r]) * rz[r]);
            acc0[f] = __builtin_amdgcn_mfma_f32_16x16x16bf16_1k(va0, e, acc0[f], 0, 0, 0);
            acc1[f] = __builtin_amdgcn_mfma_f32_16x16x16bf16_1k(va1, e, acc1[f], 0, 0, 0);
        }
    }
    int icol = i0 + lo16;
    #pragma unroll
    for (int f = 0; f < 4; ++f) {
        #pragma unroll
        for (int r = 0; r < 4; ++r) {
            oTp[(size_t)(jc * DH + hi4 + r)      * N_TOK + icol + f * 16] =
                __float2bfloat16(acc0[f][r]);
            oTp[(size_t)(jc * DH + 16 + hi4 + r) * N_TOK + icol + f * 16] =
                __float2bfloat16(acc1[f][r]);
        }
    }
}

__global__ __launch_bounds__(256) void k_fin(
        const __hip_bfloat16* __restrict__ oTp, const float* __restrict__ w4,
        const float* __restrict__ b4, const float* __restrict__ x,
        float* __restrict__ y) {
    __shared__ float w4s[64][32];
    __shared__ float tile[32][36];
    int t = threadIdx.x;
    {
        const float4* w4v = reinterpret_cast<const float4*>(w4);
        float4* dst = reinterpret_cast<float4*>(&w4s[0][0]);
        dst[t * 2]     = w4v[t * 2];
        dst[t * 2 + 1] = w4v[t * 2 + 1];
    }
    int n0 = blockIdx.x * 32;
    int d = t >> 3, seg = t & 7;
    float s[4];
    #pragma unroll
    for (int k = 0; k < 4; ++k) s[k] = 0.f;
    #pragma unroll 4
    for (int c = 0; c < NCH_O; ++c) {
        bf16x4 v = *reinterpret_cast<const bf16x4*>(
            oTp + ((size_t)c * DH + d) * N_TOK + n0 + seg * 4);
        #pragma unroll
        for (int k = 0; k < 4; ++k) s[k] += bf2f(v[k]);
    }
    #pragma unroll
    for (int k = 0; k < 4; ++k) tile[d][seg * 4 + k] = s[k];
    __syncthreads();
    int n_l = t & 31, cgr = t >> 5;
    int n = n0 + n_l, b = n >> 12, hw = n & 4095;
    #pragma unroll
    for (int ci = 0; ci < 8; ++ci) {
        int c = cgr * 8 + ci;
        float acc = b4[c];
        #pragma unroll
        for (int dd = 0; dd < 32; ++dd)
            acc = fmaf(w4s[c][dd], tile[dd][n_l], acc);
        int idx = b * (CCH * HWSZ) + c * HWSZ + hw;
        y[idx] = acc + x[idx];
    }
}

extern "C" void kernel_launch(void* const* d_in, const int* in_sizes, int n_in,
                              void* d_out, int out_size, void* d_ws, size_t ws_size,
                              hipStream_t stream) {
    const float* x  = (const float*)d_in[0];
    const float* w1 = (const float*)d_in[1];
    const float* b1 = (const float*)d_in[2];
    const float* w2 = (const float*)d_in[3];
    const float* b2 = (const float*)d_in[4];
    const float* w3 = (const float*)d_in[5];
    const float* b3 = (const float*)d_in[6];
    const float* w4 = (const float*)d_in[7];
    const float* b4 = (const float*)d_in[8];
    float* y = (float*)d_out;

    char* ws = (char*)d_ws;
    const size_t KB = 1024;
    __hip_bfloat16* Qb  = (__hip_bfloat16*)(ws);                  // 512 KB
    __hip_bfloat16* Kb  = (__hip_bfloat16*)(ws + 512 * KB);       // 512 KB
    __hip_bfloat16* VTb = (__hip_bfloat16*)(ws + 1024 * KB);      // 512 KB
    float*          Zp  = (float*)(ws + 1536 * KB);               // 1 MB
    __hip_bfloat16* oTp = (__hip_bfloat16*)(ws + 2560 * KB);      // 16 MB

    void* args[] = { (void*)&x, (void*)&w1, (void*)&b1, (void*)&w2, (void*)&b2,
                     (void*)&w3, (void*)&b3, (void*)&w4, (void*)&b4,
                     (void*)&Qb, (void*)&Kb, (void*)&VTb, (void*)&Zp,
                     (void*)&oTp, (void*)&y };
    hipError_t err = hipLaunchCooperativeKernel((const void*)k_fused,
                                                dim3(GRID_CP), dim3(256),
                                                args, 0, stream);
    if (err != hipSuccess) {
        // Fallback: verified 4-kernel pipeline (identical math and order).
        hipLaunchKernelGGL(k_qkv,   dim3(N_TOK / 8), dim3(256), 0, stream,
                           x, w1, b1, w2, b2, w3, b3, Qb, Kb, VTb);
        hipLaunchKernelGGL(k_zpart, dim3(1024), dim3(256), 0, stream, Qb, Kb, Zp);
        hipLaunchKernelGGL(k_attn,  dim3(1024), dim3(256), 0, stream,
                           Qb, Kb, VTb, Zp, oTp);
        hipLaunchKernelGGL(k_fin,   dim3(N_TOK / 32), dim3(256), 0, stream,
                           oTp, w4, b4, x, y);
    }
}

// Round 9
// 66.244 us; speedup vs baseline: 3.7080x; 3.7080x over previous
//
#include <hip/hip_runtime.h>
#include <hip/hip_bf16.h>

// Problem constants: B=2, C=64, H=64, W=64 -> N=8192 tokens, DH=32.
#define N_TOK   8192
#define DH      32
#define CCH     64
#define HWSZ    4096
#define LOG2E   1.4426950408889634f

typedef __attribute__((ext_vector_type(8))) short  bf16x8;
typedef __attribute__((ext_vector_type(4))) short  bf16x4;
typedef __attribute__((ext_vector_type(4))) float  f32x4;

// Bit-pattern f32 -> bf16 short (MFMA operand vectors ONLY — never assign
// to __hip_bfloat16, that would value-convert the integer).
static __device__ __forceinline__ short f2bf(float f) {
    __hip_bfloat16 h = __float2bfloat16(f);
    return __builtin_bit_cast(short, h);
}

// A/B fragment for mfma_f32_16x16x32_bf16 from row-major [rows][32] bf16:
// lane l supplies row row0+(l&15), k = 8*(l>>4)..+8 (16B load).
static __device__ __forceinline__ bf16x8 load_frag8(const __hip_bfloat16* __restrict__ base,
                                                    int row0, int l) {
    const __hip_bfloat16* p = base + (size_t)(row0 + (l & 15)) * DH + ((l >> 4) << 3);
    return *reinterpret_cast<const bf16x8*>(p);
}

// ---------------------------------------------------------------------------
// K1: Q,K projections only (1024 blocks, 8 tokens each). Qb pre-scaled by
// log2e. Dirty set at boundary: 1 MB.
// ---------------------------------------------------------------------------
__global__ __launch_bounds__(256) void k_qk(
        const float* __restrict__ x,
        const float* __restrict__ w1, const float* __restrict__ b1,
        const float* __restrict__ w2, const float* __restrict__ b2,
        __hip_bfloat16* __restrict__ Qb, __hip_bfloat16* __restrict__ Kb) {
    __shared__ float4 w1s[16][32];
    __shared__ float4 w2s[16][32];
    int t = threadIdx.x;
    for (int i = t; i < 512; i += 256) {
        int cg = i >> 5, d = i & 31;
        w1s[cg][d] = *reinterpret_cast<const float4*>(w1 + d * CCH + cg * 4);
        w2s[cg][d] = *reinterpret_cast<const float4*>(w2 + d * CCH + cg * 4);
    }
    __syncthreads();
    int d = t & 31, nr = t >> 5;
    int n = blockIdx.x * 8 + nr;
    int b = n >> 12, hw = n & 4095;
    const float* xp = x + (size_t)b * (CCH * HWSZ) + hw;
    float aq = b1[d], ak = b2[d];
    #pragma unroll
    for (int cg = 0; cg < 16; ++cg) {
        float x0 = xp[(cg * 4 + 0) * HWSZ];
        float x1 = xp[(cg * 4 + 1) * HWSZ];
        float x2 = xp[(cg * 4 + 2) * HWSZ];
        float x3 = xp[(cg * 4 + 3) * HWSZ];
        float4 a = w1s[cg][d];
        aq = fmaf(a.x, x0, aq); aq = fmaf(a.y, x1, aq);
        aq = fmaf(a.z, x2, aq); aq = fmaf(a.w, x3, aq);
        float4 bb = w2s[cg][d];
        ak = fmaf(bb.x, x0, ak); ak = fmaf(bb.y, x1, ak);
        ak = fmaf(bb.z, x2, ak); ak = fmaf(bb.w, x3, ak);
    }
    Qb[(size_t)n * DH + d] = __float2bfloat16(aq * LOG2E);
    Kb[(size_t)n * DH + d] = __float2bfloat16(ak);
}

// ---------------------------------------------------------------------------
// K2: block = 32 j-columns, 512 threads (8 waves). Each wave sums
// exp2(q~_i . k_j) over a 1024-row i-chunk (MFMA + shfl reduce); LDS-reduce
// the 8 wave partials (fixed order -> deterministic); project V for the
// block's own 32 tokens from x; write vpT[d][n] = v * rcp(Z) (bf16).
// Intra-block sync only. Dirty set at boundary: 0.5 MB.
// ---------------------------------------------------------------------------
__global__ __launch_bounds__(512) void k_zv(
        const float* __restrict__ x,
        const float* __restrict__ w3, const float* __restrict__ b3,
        const __hip_bfloat16* __restrict__ Qb, const __hip_bfloat16* __restrict__ Kb,
        __hip_bfloat16* __restrict__ vpT) {
    __shared__ float w3s[2048];      // [d][c] flat, 8 KB
    __shared__ float zsh[8][32];
    __shared__ float rzf[32];
    int t = threadIdx.x;
    {   // stage w3 (2048 f32)
        const float4* src = reinterpret_cast<const float4*>(w3);
        reinterpret_cast<float4*>(w3s)[t] = src[t];
    }
    int l = t & 63, w = t >> 6;
    int j0 = blockIdx.x * 32;
    bf16x8 ka0 = load_frag8(Kb, j0, l);
    bf16x8 ka1 = load_frag8(Kb, j0 + 16, l);
    float zac[8];
    #pragma unroll
    for (int k = 0; k < 8; ++k) zac[k] = 0.f;
    const f32x4 z4 = {0.f, 0.f, 0.f, 0.f};
    int i0 = w * 1024;
    #pragma unroll 2
    for (int i = i0; i < i0 + 1024; i += 16) {
        bf16x8 qf = load_frag8(Qb, i, l);
        f32x4 s0 = __builtin_amdgcn_mfma_f32_16x16x32_bf16(ka0, qf, z4, 0, 0, 0);
        f32x4 s1 = __builtin_amdgcn_mfma_f32_16x16x32_bf16(ka1, qf, z4, 0, 0, 0);
        #pragma unroll
        for (int r = 0; r < 4; ++r) {
            zac[r]     += __builtin_amdgcn_exp2f(s0[r]);
            zac[4 + r] += __builtin_amdgcn_exp2f(s1[r]);
        }
    }
    #pragma unroll
    for (int k = 0; k < 8; ++k) {
        float z = zac[k];
        z += __shfl_xor(z, 1); z += __shfl_xor(z, 2);
        z += __shfl_xor(z, 4); z += __shfl_xor(z, 8);
        zac[k] = z;
    }
    if ((l & 15) == 0) {
        int jr = (l >> 4) * 4;
        #pragma unroll
        for (int r = 0; r < 4; ++r) {
            zsh[w][jr + r]      = zac[r];
            zsh[w][16 + jr + r] = zac[4 + r];
        }
    }
    __syncthreads();
    if (t < 32) {
        float z = 0.f;
        #pragma unroll
        for (int w2 = 0; w2 < 8; ++w2) z += zsh[w2][t];
        rzf[t] = __builtin_amdgcn_rcpf(z);
    }
    __syncthreads();
    // V projection + normalize for tokens j0..j0+32.
    int jl = t & 31;
    int n  = j0 + jl;
    int b  = n >> 12, hw = n & 4095;
    const float* xp = x + (size_t)b * (CCH * HWSZ) + hw;
    int d0 = t >> 5;                 // 0..15
    float a0 = b3[d0], a1 = b3[d0 + 16];
    #pragma unroll 8
    for (int c = 0; c < CCH; ++c) {
        float xv = xp[c * HWSZ];
        a0 = fmaf(w3s[d0 * CCH + c], xv, a0);
        a1 = fmaf(w3s[(d0 + 16) * CCH + c], xv, a1);
    }
    float rz = rzf[jl];
    vpT[(size_t)d0 * N_TOK + n]        = __float2bfloat16(a0 * rz);
    vpT[(size_t)(d0 + 16) * N_TOK + n] = __float2bfloat16(a1 * rz);
}

// ---------------------------------------------------------------------------
// K3: block = 32 output rows, 512 threads (8 waves). Wave w sweeps
// j in [1024w, 1024w+1024): S^T = mfma(K,Q); P = exp2(S^T) (vpT already
// carries 1/Z); PV via mfma_16x16x16 (exp D-frag == B-operand layout).
// LDS-reduce 8 wave partials (fixed order), then conv4 + bias + residual.
// No oTp buffer, no extra kernel.
// ---------------------------------------------------------------------------
__global__ __launch_bounds__(512) void k_af(
        const __hip_bfloat16* __restrict__ Qb, const __hip_bfloat16* __restrict__ Kb,
        const __hip_bfloat16* __restrict__ vpT,
        const float* __restrict__ w4, const float* __restrict__ b4,
        const float* __restrict__ x, float* __restrict__ y) {
    __shared__ float osh[8][32][33];   // wave partials, padded
    __shared__ float w4s[2048];        // [c][d] flat, 8 KB
    __shared__ float o_red[32][33];    // [d][i], padded
    int t = threadIdx.x;
    {   // stage w4 (2048 f32)
        const float4* src = reinterpret_cast<const float4*>(w4);
        reinterpret_cast<float4*>(w4s)[t] = src[t];
    }
    int l = t & 63, w = t >> 6;
    int i0 = blockIdx.x * 32;
    bf16x8 qb0 = load_frag8(Qb, i0, l);
    bf16x8 qb1 = load_frag8(Qb, i0 + 16, l);
    f32x4 a00 = {0.f,0.f,0.f,0.f}, a01 = a00, a10 = a00, a11 = a00;
    const f32x4 z4 = {0.f, 0.f, 0.f, 0.f};
    int lo16 = l & 15, hi4 = (l >> 4) << 2;
    const __hip_bfloat16* v0p = vpT + (size_t)lo16 * N_TOK;
    const __hip_bfloat16* v1p = vpT + (size_t)(lo16 + 16) * N_TOK;
    int jbase = w * 1024;
    #pragma unroll 2
    for (int jl = 0; jl < 1024; jl += 16) {
        int j = jbase + jl;
        bf16x8 kaf = load_frag8(Kb, j, l);
        bf16x4 va0 = *reinterpret_cast<const bf16x4*>(v0p + j + hi4);
        bf16x4 va1 = *reinterpret_cast<const bf16x4*>(v1p + j + hi4);
        f32x4 s0 = __builtin_amdgcn_mfma_f32_16x16x32_bf16(kaf, qb0, z4, 0, 0, 0);
        f32x4 s1 = __builtin_amdgcn_mfma_f32_16x16x32_bf16(kaf, qb1, z4, 0, 0, 0);
        bf16x4 e0, e1;
        #pragma unroll
        for (int r = 0; r < 4; ++r) {
            e0[r] = f2bf(__builtin_amdgcn_exp2f(s0[r]));
            e1[r] = f2bf(__builtin_amdgcn_exp2f(s1[r]));
        }
        a00 = __builtin_amdgcn_mfma_f32_16x16x16bf16_1k(va0, e0, a00, 0, 0, 0);
        a01 = __builtin_amdgcn_mfma_f32_16x16x16bf16_1k(va1, e0, a01, 0, 0, 0);
        a10 = __builtin_amdgcn_mfma_f32_16x16x16bf16_1k(va0, e1, a10, 0, 0, 0);
        a11 = __builtin_amdgcn_mfma_f32_16x16x16bf16_1k(va1, e1, a11, 0, 0, 0);
    }
    // stash wave partials: o^T[d][i], d = 16h+hi4+r, i = 16g+lo16
    #pragma unroll
    for (int r = 0; r < 4; ++r) {
        osh[w][hi4 + r][lo16]           = a00[r];
        osh[w][16 + hi4 + r][lo16]      = a01[r];
        osh[w][hi4 + r][16 + lo16]      = a10[r];
        osh[w][16 + hi4 + r][16 + lo16] = a11[r];
    }
    __syncthreads();
    // reduce 8 partials (fixed order -> deterministic)
    #pragma unroll
    for (int idx = t; idx < 1024; idx += 512) {
        int d = idx >> 5, i = idx & 31;
        float o = 0.f;
        #pragma unroll
        for (int w2 = 0; w2 < 8; ++w2) o += osh[w2][d][i];
        o_red[d][i] = o;
    }
    __syncthreads();
    // conv4 + bias + residual for 32 tokens x 64 channels
    int i = t & 31, c0 = t >> 5;        // c0 0..15
    int n = i0 + i, b = n >> 12, hw = n & 4095;
    #pragma unroll
    for (int c = c0; c < CCH; c += 16) {
        float acc = b4[c];
        #pragma unroll
        for (int d = 0; d < DH; ++d)
            acc = fmaf(w4s[c * DH + d], o_red[d][i], acc);
        size_t idx = (size_t)b * (CCH * HWSZ) + (size_t)c * HWSZ + hw;
        y[idx] = acc + x[idx];
    }
}

extern "C" void kernel_launch(void* const* d_in, const int* in_sizes, int n_in,
                              void* d_out, int out_size, void* d_ws, size_t ws_size,
                              hipStream_t stream) {
    const float* x  = (const float*)d_in[0];
    const float* w1 = (const float*)d_in[1];
    const float* b1 = (const float*)d_in[2];
    const float* w2 = (const float*)d_in[3];
    const float* b2 = (const float*)d_in[4];
    const float* w3 = (const float*)d_in[5];
    const float* b3 = (const float*)d_in[6];
    const float* w4 = (const float*)d_in[7];
    const float* b4 = (const float*)d_in[8];
    float* y = (float*)d_out;

    char* ws = (char*)d_ws;
    const size_t KB = 1024;
    __hip_bfloat16* Qb  = (__hip_bfloat16*)(ws);                  // 512 KB
    __hip_bfloat16* Kb  = (__hip_bfloat16*)(ws + 512 * KB);       // 512 KB
    __hip_bfloat16* vpT = (__hip_bfloat16*)(ws + 1024 * KB);      // 512 KB

    hipLaunchKernelGGL(k_qk, dim3(N_TOK / 8), dim3(256), 0, stream,
                       x, w1, b1, w2, b2, Qb, Kb);
    hipLaunchKernelGGL(k_zv, dim3(N_TOK / 32), dim3(512), 0, stream,
                       x, w3, b3, Qb, Kb, vpT);
    hipLaunchKernelGGL(k_af, dim3(N_TOK / 32), dim3(512), 0, stream,
                       Qb, Kb, vpT, w4, b4, x, y);
}

// Round 10
// 63.148 us; speedup vs baseline: 3.8897x; 1.0490x over previous
//
#include <hip/hip_runtime.h>
#include <hip/hip_bf16.h>

// Problem constants: B=2, C=64, H=64, W=64 -> N=8192 tokens, DH=32.
#define N_TOK   8192
#define DH      32
#define CCH     64
#define HWSZ    4096
#define LOG2E   1.4426950408889634f

typedef __attribute__((ext_vector_type(8))) short  bf16x8;
typedef __attribute__((ext_vector_type(4))) short  bf16x4;
typedef __attribute__((ext_vector_type(4))) float  f32x4;

// Bit-pattern f32 -> bf16 short (MFMA operand vectors ONLY — never assign
// to __hip_bfloat16, that would value-convert the integer).
static __device__ __forceinline__ short f2bf(float f) {
    __hip_bfloat16 h = __float2bfloat16(f);
    return __builtin_bit_cast(short, h);
}

// A/B fragment for mfma_f32_16x16x32_bf16 from row-major [rows][32] bf16:
// lane l supplies row row0+(l&15), k = 8*(l>>4)..+8 (16B load).
static __device__ __forceinline__ bf16x8 load_frag8(const __hip_bfloat16* __restrict__ base,
                                                    int row0, int l) {
    const __hip_bfloat16* p = base + (size_t)(row0 + (l & 15)) * DH + ((l >> 4) << 3);
    return *reinterpret_cast<const bf16x8*>(p);
}

// ---------------------------------------------------------------------------
// K1: Q,K projections (1024 blocks, 8 tokens each). Qb pre-scaled by log2e.
// ---------------------------------------------------------------------------
__global__ __launch_bounds__(256) void k_qk(
        const float* __restrict__ x,
        const float* __restrict__ w1, const float* __restrict__ b1,
        const float* __restrict__ w2, const float* __restrict__ b2,
        __hip_bfloat16* __restrict__ Qb, __hip_bfloat16* __restrict__ Kb) {
    __shared__ float4 w1s[16][32];
    __shared__ float4 w2s[16][32];
    int t = threadIdx.x;
    for (int i = t; i < 512; i += 256) {
        int cg = i >> 5, d = i & 31;
        w1s[cg][d] = *reinterpret_cast<const float4*>(w1 + d * CCH + cg * 4);
        w2s[cg][d] = *reinterpret_cast<const float4*>(w2 + d * CCH + cg * 4);
    }
    __syncthreads();
    int d = t & 31, nr = t >> 5;
    int n = blockIdx.x * 8 + nr;
    int b = n >> 12, hw = n & 4095;
    const float* xp = x + (size_t)b * (CCH * HWSZ) + hw;
    float aq = b1[d], ak = b2[d];
    #pragma unroll
    for (int cg = 0; cg < 16; ++cg) {
        float x0 = xp[(cg * 4 + 0) * HWSZ];
        float x1 = xp[(cg * 4 + 1) * HWSZ];
        float x2 = xp[(cg * 4 + 2) * HWSZ];
        float x3 = xp[(cg * 4 + 3) * HWSZ];
        float4 a = w1s[cg][d];
        aq = fmaf(a.x, x0, aq); aq = fmaf(a.y, x1, aq);
        aq = fmaf(a.z, x2, aq); aq = fmaf(a.w, x3, aq);
        float4 bb = w2s[cg][d];
        ak = fmaf(bb.x, x0, ak); ak = fmaf(bb.y, x1, ak);
        ak = fmaf(bb.z, x2, ak); ak = fmaf(bb.w, x3, ak);
    }
    Qb[(size_t)n * DH + d] = __float2bfloat16(aq * LOG2E);
    Kb[(size_t)n * DH + d] = __float2bfloat16(ak);
}

// ---------------------------------------------------------------------------
// K2: block = 32 j-columns, 1024 threads (16 waves). Wave w sums
// exp2(q~_i . k_j) over i in [512w, 512w+512) (MFMA + shfl reduce);
// LDS-reduce the 16 wave partials (fixed order -> deterministic); project V
// for the block's own 32 tokens from x; write vpT[d][n] = v*rcp(Z) (bf16).
// ---------------------------------------------------------------------------
__global__ __launch_bounds__(1024, 1) void k_zv(
        const float* __restrict__ x,
        const float* __restrict__ w3, const float* __restrict__ b3,
        const __hip_bfloat16* __restrict__ Qb, const __hip_bfloat16* __restrict__ Kb,
        __hip_bfloat16* __restrict__ vpT) {
    __shared__ float w3s[2048];      // [d][c] flat, 8 KB
    __shared__ float zsh[16][32];
    __shared__ float rzf[32];
    int t = threadIdx.x;
    if (t < 512) {   // stage w3 (2048 f32)
        const float4* src = reinterpret_cast<const float4*>(w3);
        reinterpret_cast<float4*>(w3s)[t] = src[t];
    }
    int l = t & 63, w = t >> 6;      // 16 waves
    int j0 = blockIdx.x * 32;
    bf16x8 ka0 = load_frag8(Kb, j0, l);
    bf16x8 ka1 = load_frag8(Kb, j0 + 16, l);
    float zac[8];
    #pragma unroll
    for (int k = 0; k < 8; ++k) zac[k] = 0.f;
    const f32x4 z4 = {0.f, 0.f, 0.f, 0.f};
    int i0 = w * 512;
    #pragma unroll 2
    for (int i = i0; i < i0 + 512; i += 16) {
        bf16x8 qf = load_frag8(Qb, i, l);
        f32x4 s0 = __builtin_amdgcn_mfma_f32_16x16x32_bf16(ka0, qf, z4, 0, 0, 0);
        f32x4 s1 = __builtin_amdgcn_mfma_f32_16x16x32_bf16(ka1, qf, z4, 0, 0, 0);
        #pragma unroll
        for (int r = 0; r < 4; ++r) {
            zac[r]     += __builtin_amdgcn_exp2f(s0[r]);
            zac[4 + r] += __builtin_amdgcn_exp2f(s1[r]);
        }
    }
    #pragma unroll
    for (int k = 0; k < 8; ++k) {
        float z = zac[k];
        z += __shfl_xor(z, 1); z += __shfl_xor(z, 2);
        z += __shfl_xor(z, 4); z += __shfl_xor(z, 8);
        zac[k] = z;
    }
    if ((l & 15) == 0) {
        int jr = (l >> 4) * 4;
        #pragma unroll
        for (int r = 0; r < 4; ++r) {
            zsh[w][jr + r]      = zac[r];
            zsh[w][16 + jr + r] = zac[4 + r];
        }
    }
    __syncthreads();
    if (t < 32) {
        float z = 0.f;
        #pragma unroll
        for (int w2 = 0; w2 < 16; ++w2) z += zsh[w2][t];
        rzf[t] = __builtin_amdgcn_rcpf(z);
    }
    __syncthreads();
    // V projection + normalize: thread -> one (d, token) pair.
    int jl = t & 31;
    int d0 = t >> 5;                 // 0..31
    int n  = j0 + jl;
    int b  = n >> 12, hw = n & 4095;
    const float* xp = x + (size_t)b * (CCH * HWSZ) + hw;
    float a0 = b3[d0];
    #pragma unroll 8
    for (int c = 0; c < CCH; ++c)
        a0 = fmaf(w3s[d0 * CCH + c], xp[c * HWSZ], a0);
    vpT[(size_t)d0 * N_TOK + n] = __float2bfloat16(a0 * rzf[jl]);
}

// ---------------------------------------------------------------------------
// K3: block = 32 output rows, 1024 threads (16 waves, 4/SIMD). Wave w sweeps
// j in [512w, 512w+512): S^T = mfma(K,Q); P = exp2(S^T) (vpT pre-normalized);
// PV via mfma_16x16x16 (exp D-frag == B-operand layout). Two-round LDS
// partial reduce (fits 64KB static-LDS limit), then conv4 + bias + residual.
// ---------------------------------------------------------------------------
__global__ __launch_bounds__(1024, 1) void k_af(
        const __hip_bfloat16* __restrict__ Qb, const __hip_bfloat16* __restrict__ Kb,
        const __hip_bfloat16* __restrict__ vpT,
        const float* __restrict__ w4, const float* __restrict__ b4,
        const float* __restrict__ x, float* __restrict__ y) {
    __shared__ float osh[8][32][36];   // wave-pair partials (36: 2-way banks max)
    __shared__ float w4s[2048];        // [c][d] flat, 8 KB
    __shared__ float o_red[32][36];    // [d][i]
    int t = threadIdx.x;
    if (t < 512) {   // stage w4 (2048 f32)
        const float4* src = reinterpret_cast<const float4*>(w4);
        reinterpret_cast<float4*>(w4s)[t] = src[t];
    }
    int l = t & 63, w = t >> 6;        // 16 waves
    int i0 = blockIdx.x * 32;
    bf16x8 qb0 = load_frag8(Qb, i0, l);
    bf16x8 qb1 = load_frag8(Qb, i0 + 16, l);
    f32x4 a00 = {0.f,0.f,0.f,0.f}, a01 = a00, a10 = a00, a11 = a00;
    const f32x4 z4 = {0.f, 0.f, 0.f, 0.f};
    int lo16 = l & 15, hi4 = (l >> 4) << 2;
    const __hip_bfloat16* v0p = vpT + (size_t)lo16 * N_TOK;
    const __hip_bfloat16* v1p = vpT + (size_t)(lo16 + 16) * N_TOK;
    int jbase = w * 512;
    #pragma unroll 2
    for (int jl = 0; jl < 512; jl += 16) {
        int j = jbase + jl;
        bf16x8 kaf = load_frag8(Kb, j, l);
        bf16x4 va0 = *reinterpret_cast<const bf16x4*>(v0p + j + hi4);
        bf16x4 va1 = *reinterpret_cast<const bf16x4*>(v1p + j + hi4);
        f32x4 s0 = __builtin_amdgcn_mfma_f32_16x16x32_bf16(kaf, qb0, z4, 0, 0, 0);
        f32x4 s1 = __builtin_amdgcn_mfma_f32_16x16x32_bf16(kaf, qb1, z4, 0, 0, 0);
        bf16x4 e0, e1;
        #pragma unroll
        for (int r = 0; r < 4; ++r) {
            e0[r] = f2bf(__builtin_amdgcn_exp2f(s0[r]));
            e1[r] = f2bf(__builtin_amdgcn_exp2f(s1[r]));
        }
        a00 = __builtin_amdgcn_mfma_f32_16x16x16bf16_1k(va0, e0, a00, 0, 0, 0);
        a01 = __builtin_amdgcn_mfma_f32_16x16x16bf16_1k(va1, e0, a01, 0, 0, 0);
        a10 = __builtin_amdgcn_mfma_f32_16x16x16bf16_1k(va0, e1, a10, 0, 0, 0);
        a11 = __builtin_amdgcn_mfma_f32_16x16x16bf16_1k(va1, e1, a11, 0, 0, 0);
    }
    // Two-round partial stash: waves 0-7 write, waves 8-15 accumulate.
    if (w < 8) {
        #pragma unroll
        for (int r = 0; r < 4; ++r) {
            osh[w][hi4 + r][lo16]           = a00[r];
            osh[w][16 + hi4 + r][lo16]      = a01[r];
            osh[w][hi4 + r][16 + lo16]      = a10[r];
            osh[w][16 + hi4 + r][16 + lo16] = a11[r];
        }
    }
    __syncthreads();
    if (w >= 8) {
        int ws = w - 8;
        #pragma unroll
        for (int r = 0; r < 4; ++r) {
            osh[ws][hi4 + r][lo16]           += a00[r];
            osh[ws][16 + hi4 + r][lo16]      += a01[r];
            osh[ws][hi4 + r][16 + lo16]      += a10[r];
            osh[ws][16 + hi4 + r][16 + lo16] += a11[r];
        }
    }
    __syncthreads();
    // reduce 8 slices (fixed order -> deterministic): one cell per thread
    {
        int d = t >> 5, i = t & 31;
        float o = 0.f;
        #pragma unroll
        for (int w2 = 0; w2 < 8; ++w2) o += osh[w2][d][i];
        o_red[d][i] = o;
    }
    __syncthreads();
    // conv4 + bias + residual: 32 tokens x 64 channels, 2 channels/thread
    int i = t & 31, c0 = t >> 5;        // c0 0..31
    int n = i0 + i, b = n >> 12, hw = n & 4095;
    #pragma unroll
    for (int c = c0; c < CCH; c += 32) {
        float acc = b4[c];
        #pragma unroll
        for (int d = 0; d < DH; ++d)
            acc = fmaf(w4s[c * DH + d], o_red[d][i], acc);
        size_t idx = (size_t)b * (CCH * HWSZ) + (size_t)c * HWSZ + hw;
        y[idx] = acc + x[idx];
    }
}

extern "C" void kernel_launch(void* const* d_in, const int* in_sizes, int n_in,
                              void* d_out, int out_size, void* d_ws, size_t ws_size,
                              hipStream_t stream) {
    const float* x  = (const float*)d_in[0];
    const float* w1 = (const float*)d_in[1];
    const float* b1 = (const float*)d_in[2];
    const float* w2 = (const float*)d_in[3];
    const float* b2 = (const float*)d_in[4];
    const float* w3 = (const float*)d_in[5];
    const float* b3 = (const float*)d_in[6];
    const float* w4 = (const float*)d_in[7];
    const float* b4 = (const float*)d_in[8];
    float* y = (float*)d_out;

    char* ws = (char*)d_ws;
    const size_t KB = 1024;
    __hip_bfloat16* Qb  = (__hip_bfloat16*)(ws);                  // 512 KB
    __hip_bfloat16* Kb  = (__hip_bfloat16*)(ws + 512 * KB);       // 512 KB
    __hip_bfloat16* vpT = (__hip_bfloat16*)(ws + 1024 * KB);      // 512 KB

    hipLaunchKernelGGL(k_qk, dim3(N_TOK / 8), dim3(256), 0, stream,
                       x, w1, b1, w2, b2, Qb, Kb);
    hipLaunchKernelGGL(k_zv, dim3(N_TOK / 32), dim3(1024), 0, stream,
                       x, w3, b3, Qb, Kb, vpT);
    hipLaunchKernelGGL(k_af, dim3(N_TOK / 32), dim3(1024), 0, stream,
                       Qb, Kb, vpT, w4, b4, x, y);
}